// Round 6
// baseline (3448.116 us; speedup 1.0000x reference)
//
#include <hip/hip_runtime.h>
#include <stdint.h>

// Problem constants (from reference)
#define NN      5000
#define NE      4000
#define NB      8
#define TSTEPS  256
#define NDELAY  15
#define NW      157          // uint32 words covering 5000 presyn bits
#define NIPAD   5120         // padded neuron dim (columns of maskT2)
#define RW      160          // ring/mask row stride in words
#define IPB     256          // threads per block
#define BPB     20           // blocks per batch
#define NBLK    (NB*BPB)     // 160 blocks -> 1 per CU, co-resident
#define RING_SLOTS 32
#define CH      4            // chunk length (64 chunks, no tail)
#define NCHUNK  (TSTEPS/CH)  // 64
#define BARSTRIDE 16         // ints between chunk counters (64B apart)

// Workspace layout (bytes)
#define MASK_BYTES (RW*NIPAD*4)          // 3,276,800
#define BAR_OFF    MASK_BYTES
#define BAR_BYTES  (64*BARSTRIDE*4)      // 4,096 (64 chunk counters)
#define RING_OFF   (BAR_OFF + BAR_BYTES)
#define RING_BYTES (RING_SLOTS*NB*RW*4)  // 163,840
#define ZERO_BYTES (RING_OFF + RING_BYTES)

// ---------------------------------------------------------------------------
// Kernel 1: bit-pack connectivity, word-major-transposed:
//   maskT2[w*NIPAD + i] bit (j&31), w=j>>5, set iff W[i,j] != 0.
// ---------------------------------------------------------------------------
__global__ void _Brunel_build_mask(const float* __restrict__ W,
                                   uint32_t* __restrict__ maskT2)
{
    int j = blockIdx.x * blockDim.x + threadIdx.x;   // presyn 0..5119
    int i = blockIdx.y;                              // postsyn row 0..4999
    int lane = threadIdx.x & 63;
    bool nz = false;
    if (j < NN) nz = (W[(size_t)i * NN + j] != 0.0f);
    unsigned long long m = __ballot(nz);
    if ((lane & 31) == 0 && j < NN) {
        uint32_t wd = (lane == 0) ? (uint32_t)m : (uint32_t)(m >> 32);
        maskT2[(size_t)(j >> 5) * NIPAD + i] = wd;
    }
}

// ---------------------------------------------------------------------------
// Kernel 2: persistent SNN sim. The mask lives in LDS (thread-private rows),
// loaded ONCE; registers hold only tiny state. Per chunk (CH=4 steps):
// stage 4 delayed spike-word sets -> LDS, then each mask uint4 is read once
// and ANDed against 4 uniform spike uint4s (broadcast reads), popc-accum.
// Per-chunk arrival counters barc[m]; wait at m polls barc[m-3]==NBLK.
// ---------------------------------------------------------------------------
__global__ void __launch_bounds__(IPB, 1) _Brunel_persist(
    const float* __restrict__ ext,
    const uint32_t* __restrict__ maskT2,
    uint32_t* __restrict__ ring,
    int* __restrict__ barc,
    float* __restrict__ out_spk,
    float* __restrict__ out_vs)
{
    const int tx   = threadIdx.x;
    const int bb   = blockIdx.x;
    const int b    = bb / BPB;
    const int i    = (bb % BPB) * IPB + tx;
    const bool act = (i < NN);
    const int lane = tx & 63;

    // LDS: mask rows (thread-private), stride 156 words = 624B (16B-aligned)
    __shared__ __align__(16) uint32_t s_mask[IPB][156];   // 159,744 B
    __shared__ uint32_t s_mask156[IPB];                   //   1,024 B
    __shared__ __align__(16) uint32_t s_spk[CH][RW];      //   2,560 B
                                                          // total 163,328 B

    // ---- one-time: mask row -> LDS (global reads coalesced over tx) ----
#pragma unroll 8
    for (int w = 0; w < NW; ++w) {
        uint32_t mv = maskT2[(size_t)w * NIPAD + i];      // pad cols are 0
        if (w < 156) s_mask[tx][w] = mv; else s_mask156[tx] = mv;
    }
    // zero spike staging (chunks 0..2 never stage; counts must be 0)
    for (int idx = tx; idx < CH * RW; idx += IPB)
        ((uint32_t*)s_spk)[idx] = 0u;
    __syncthreads();

    float v = 0.0f;

    for (int t0 = 0, m = 0; t0 < TSTEPS; t0 += CH, ++m) {
        // ---- prefetch external inputs (HBM latency hides under poll) ----
        float x0 = 0.f, x1 = 0.f, x2 = 0.f, x3 = 0.f;
        if (act) {
            const float* e0 = ext + ((size_t)t0 * NB + b) * NN + i;
            const size_t st = (size_t)NB * NN;
            x0 = e0[0]; x1 = e0[st]; x2 = e0[2 * st]; x3 = e0[3 * st];
        }

        // ---- wait for chunk m-3, then stage 4 delayed spike slots ----
        if (m >= 3) {
            if (tx == 0) {
                const int* c3 = barc + (size_t)(m - 3) * BARSTRIDE;
                while (__hip_atomic_load(c3, __ATOMIC_RELAXED,
                                         __HIP_MEMORY_SCOPE_AGENT) < NBLK)
                    __builtin_amdgcn_s_sleep(2);
            }
            __syncthreads();
            __threadfence();                 // acquire
            const int ts0 = t0 - NDELAY;     // may be -3 at m=3: slots hold 0
#pragma unroll
            for (int it = 0; it < (CH * RW + IPB - 1) / IPB; ++it) {
                int idx = tx + it * IPB;
                if (idx < CH * RW) {
                    int k = idx / RW, w = idx - k * RW;
                    int ts = ts0 + k;
                    ((uint32_t*)s_spk)[idx] =
                        ring[((size_t)(ts & (RING_SLOTS - 1)) * NB + b) * RW + w];
                }
            }
            __syncthreads();
        }

        // ---- synapse counts: mask uint4 read ONCE, used for all 4 steps ----
        int cE[CH] = {0, 0, 0, 0};
        int cI[CH] = {0, 0, 0, 0};
#pragma unroll
        for (int c = 0; c < 39; ++c) {
            uint4 m4 = *(const uint4*)&s_mask[tx][4 * c];
#pragma unroll
            for (int k = 0; k < CH; ++k) {
                uint4 s4 = *(const uint4*)&s_spk[k][4 * c];
                // word w = 4c+q is excitatory iff w < 125
                if (4 * c + 0 < 125) cE[k] += __popc(m4.x & s4.x);
                else                 cI[k] += __popc(m4.x & s4.x);
                if (4 * c + 1 < 125) cE[k] += __popc(m4.y & s4.y);
                else                 cI[k] += __popc(m4.y & s4.y);
                if (4 * c + 2 < 125) cE[k] += __popc(m4.z & s4.z);
                else                 cI[k] += __popc(m4.z & s4.z);
                if (4 * c + 3 < 125) cE[k] += __popc(m4.w & s4.w);
                else                 cI[k] += __popc(m4.w & s4.w);
            }
        }
        {
            uint32_t mL = s_mask156[tx];     // word 156 (inhibitory)
#pragma unroll
            for (int k = 0; k < CH; ++k) cI[k] += __popc(mL & s_spk[k][156]);
        }

        // ---- 4 sequential neuron updates ----
#pragma unroll
        for (int k = 0; k < CH; ++k) {
            const int t = t0 + k;
            float x = (k == 0) ? x0 : (k == 1) ? x1 : (k == 2) ? x2 : x3;
            float cur = 0.1f * (float)cE[k] - 0.5f * (float)cI[k];
            v = v * 0.95f + (cur + x);
            bool s = act && (v >= 1.0f);
            float sflag = s ? 1.0f : 0.0f;
            float vout  = s ? 0.0f : v;
            if (act) {
                size_t o = ((size_t)t * NB + b) * NN + i;
                out_spk[o] = sflag;
                out_vs[o]  = vout;
            }
            v = vout;

            // pack spikes into the ring (2 words per wave)
            unsigned long long bm = __ballot(s);
            if ((lane & 31) == 0 && act) {
                uint32_t wd = (lane == 0) ? (uint32_t)bm : (uint32_t)(bm >> 32);
                ring[((size_t)(t & (RING_SLOTS - 1)) * NB + b) * RW + (i >> 5)] = wd;
            }
        }

        // ---- arrive: release fence, one per-chunk atomic per block ----
        __threadfence();
        __syncthreads();
        if (tx == 0) atomicAdd(barc + (size_t)m * BARSTRIDE, 1);
    }
}

// ---------------------------------------------------------------------------
extern "C" void kernel_launch(void* const* d_in, const int* in_sizes, int n_in,
                              void* d_out, int out_size, void* d_ws, size_t ws_size,
                              hipStream_t stream)
{
    const float* ext = (const float*)d_in[0];   // [T,B,N] fp32
    const float* W   = (const float*)d_in[1];   // [N,N]   fp32

    float* out_spk = (float*)d_out;                          // [T,B,N]
    float* out_vs  = out_spk + (size_t)TSTEPS * NB * NN;     // [T,B,N]

    uint8_t*  ws   = (uint8_t*)d_ws;
    uint32_t* mask = (uint32_t*)(ws);
    int*      barc = (int*)(ws + BAR_OFF);
    uint32_t* ring = (uint32_t*)(ws + RING_OFF);

    // zero mask (pad columns must read 0) + per-chunk counters + ring
    hipMemsetAsync(ws, 0, ZERO_BYTES, stream);

    dim3 gmask(NIPAD / IPB, NN);   // (20, 5000)
    _Brunel_build_mask<<<gmask, IPB, 0, stream>>>(W, mask);

    _Brunel_persist<<<NBLK, IPB, 0, stream>>>(ext, mask, ring, barc,
                                              out_spk, out_vs);
}

// Round 7
// 1787.354 us; speedup vs baseline: 1.9292x; 1.9292x over previous
//
#include <hip/hip_runtime.h>
#include <stdint.h>

// Problem constants (from reference)
#define NN      5000
#define NE      4000
#define NB      8
#define TSTEPS  256
#define NDELAY  15
#define NW      157          // uint32 words covering 5000 presyn bits
#define NIPAD   5120         // padded neuron dim (columns of maskT2)
#define RW      160          // ring/mask row stride in words
#define IPB     256          // threads per block
#define BPB     20           // blocks per batch
#define NBLK    (NB*BPB)     // 160 blocks -> 1 per CU, co-resident
#define RING_SLOTS 32
#define CH      4            // chunk length (64 chunks, no tail)
#define BARSTRIDE 16         // ints between chunk counters (64B apart)

// Workspace layout (bytes)
#define MASK_BYTES (RW*NIPAD*4)          // 3,276,800
#define BAR_OFF    MASK_BYTES
#define BAR_BYTES  (64*BARSTRIDE*4)      // 4,096 (64 chunk counters)
#define RING_OFF   (BAR_OFF + BAR_BYTES)
#define RING_BYTES (RING_SLOTS*NB*RW*4)  // 163,840
#define ZERO_BYTES (RING_OFF + RING_BYTES)

// ---------------------------------------------------------------------------
// Kernel 1: bit-pack connectivity, word-major-transposed:
//   maskT2[w*NIPAD + i] bit (j&31), w=j>>5, set iff W[i,j] != 0.
// ---------------------------------------------------------------------------
__global__ void _Brunel_build_mask(const float* __restrict__ W,
                                   uint32_t* __restrict__ maskT2)
{
    int j = blockIdx.x * blockDim.x + threadIdx.x;   // presyn 0..5119
    int i = blockIdx.y;                              // postsyn row 0..4999
    int lane = threadIdx.x & 63;
    bool nz = false;
    if (j < NN) nz = (W[(size_t)i * NN + j] != 0.0f);
    unsigned long long m = __ballot(nz);
    if ((lane & 31) == 0 && j < NN) {
        uint32_t wd = (lane == 0) ? (uint32_t)m : (uint32_t)(m >> 32);
        maskT2[(size_t)(j >> 5) * NIPAD + i] = wd;
    }
}

// ---------------------------------------------------------------------------
// Kernel 2: persistent SNN sim. Mask in LDS (thread-private rows), loaded
// once. Per chunk (CH=4): stage 4 delayed spike-word sets, then each mask
// uint4 is read ONCE and ANDed against 4 uniform spike uint4s.
// Round-7 fix vs round 6: bounded unroll + branch-free word segments +
// named scalar accumulators -> no full-unroll register blow-up / scratch
// spill (round 6: 2 GB of spill traffic, VGPR=256).
// ---------------------------------------------------------------------------
__global__ void __launch_bounds__(IPB, 1) _Brunel_persist(
    const float* __restrict__ ext,
    const uint32_t* __restrict__ maskT2,
    uint32_t* __restrict__ ring,
    int* __restrict__ barc,
    float* __restrict__ out_spk,
    float* __restrict__ out_vs)
{
    const int tx   = threadIdx.x;
    const int bb   = blockIdx.x;
    const int b    = bb / BPB;
    const int i    = (bb % BPB) * IPB + tx;
    const bool act = (i < NN);
    const int lane = tx & 63;

    // LDS: mask rows (thread-private), stride 156 words = 624B (16B-aligned)
    __shared__ __align__(16) uint32_t s_mask[IPB][156];   // 159,744 B
    __shared__ uint32_t s_mask156[IPB];                   //   1,024 B
    __shared__ __align__(16) uint32_t s_spk[CH][RW];      //   2,560 B
                                                          // total 163,328 B

    // ---- one-time: mask row -> LDS (global reads coalesced over tx) ----
    for (int w = 0; w < NW; ++w) {
        uint32_t mv = maskT2[(size_t)w * NIPAD + i];      // pad cols are 0
        if (w < 156) s_mask[tx][w] = mv; else s_mask156[tx] = mv;
    }
    // zero spike staging (chunks 0..2 never stage; counts must be 0)
    for (int idx = tx; idx < CH * RW; idx += IPB)
        ((uint32_t*)s_spk)[idx] = 0u;
    __syncthreads();

    float v = 0.0f;

    for (int t0 = 0, m = 0; t0 < TSTEPS; t0 += CH, ++m) {
        // ---- prefetch external inputs (HBM latency hides under poll) ----
        float x0 = 0.f, x1 = 0.f, x2 = 0.f, x3 = 0.f;
        if (act) {
            const float* e0 = ext + ((size_t)t0 * NB + b) * NN + i;
            const size_t st = (size_t)NB * NN;
            x0 = e0[0]; x1 = e0[st]; x2 = e0[2 * st]; x3 = e0[3 * st];
        }

        // ---- wait for chunk m-3, then stage 4 delayed spike slots ----
        if (m >= 3) {
            if (tx == 0) {
                const int* c3 = barc + (size_t)(m - 3) * BARSTRIDE;
                while (__hip_atomic_load(c3, __ATOMIC_RELAXED,
                                         __HIP_MEMORY_SCOPE_AGENT) < NBLK)
                    __builtin_amdgcn_s_sleep(2);
            }
            __syncthreads();
            __threadfence();                 // acquire
            const int ts0 = t0 - NDELAY;     // may be -3 at m=3: slots hold 0
            for (int it = 0; it < (CH * RW + IPB - 1) / IPB; ++it) {
                int idx = tx + it * IPB;
                if (idx < CH * RW) {
                    int k = idx / RW, w = idx - k * RW;
                    int ts = ts0 + k;
                    ((uint32_t*)s_spk)[idx] =
                        ring[((size_t)(ts & (RING_SLOTS - 1)) * NB + b) * RW + w];
                }
            }
            __syncthreads();
        }

        // ---- synapse counts: mask uint4 read ONCE, used for all 4 steps ----
        int cE0 = 0, cE1 = 0, cE2 = 0, cE3 = 0;
        int cI0 = 0, cI1 = 0, cI2 = 0, cI3 = 0;
        const uint32_t* __restrict__ mrow = s_mask[tx];

#pragma unroll 4                       // bounded: no full-unroll spill
        for (int c = 0; c < 31; ++c) { // words 0..123: all excitatory
            uint4 m4 = *(const uint4*)(mrow + 4 * c);
            uint4 a0 = *(const uint4*)(&s_spk[0][4 * c]);
            uint4 a1 = *(const uint4*)(&s_spk[1][4 * c]);
            uint4 a2 = *(const uint4*)(&s_spk[2][4 * c]);
            uint4 a3 = *(const uint4*)(&s_spk[3][4 * c]);
            cE0 += __popc(m4.x & a0.x) + __popc(m4.y & a0.y)
                 + __popc(m4.z & a0.z) + __popc(m4.w & a0.w);
            cE1 += __popc(m4.x & a1.x) + __popc(m4.y & a1.y)
                 + __popc(m4.z & a1.z) + __popc(m4.w & a1.w);
            cE2 += __popc(m4.x & a2.x) + __popc(m4.y & a2.y)
                 + __popc(m4.z & a2.z) + __popc(m4.w & a2.w);
            cE3 += __popc(m4.x & a3.x) + __popc(m4.y & a3.y)
                 + __popc(m4.z & a3.z) + __popc(m4.w & a3.w);
        }
        {   // c = 31: word 124 excitatory, words 125..127 inhibitory
            uint4 m4 = *(const uint4*)(mrow + 124);
            uint4 a0 = *(const uint4*)(&s_spk[0][124]);
            uint4 a1 = *(const uint4*)(&s_spk[1][124]);
            uint4 a2 = *(const uint4*)(&s_spk[2][124]);
            uint4 a3 = *(const uint4*)(&s_spk[3][124]);
            cE0 += __popc(m4.x & a0.x);
            cI0 += __popc(m4.y & a0.y) + __popc(m4.z & a0.z) + __popc(m4.w & a0.w);
            cE1 += __popc(m4.x & a1.x);
            cI1 += __popc(m4.y & a1.y) + __popc(m4.z & a1.z) + __popc(m4.w & a1.w);
            cE2 += __popc(m4.x & a2.x);
            cI2 += __popc(m4.y & a2.y) + __popc(m4.z & a2.z) + __popc(m4.w & a2.w);
            cE3 += __popc(m4.x & a3.x);
            cI3 += __popc(m4.y & a3.y) + __popc(m4.z & a3.z) + __popc(m4.w & a3.w);
        }
#pragma unroll 4
        for (int c = 32; c < 39; ++c) { // words 128..155: all inhibitory
            uint4 m4 = *(const uint4*)(mrow + 4 * c);
            uint4 a0 = *(const uint4*)(&s_spk[0][4 * c]);
            uint4 a1 = *(const uint4*)(&s_spk[1][4 * c]);
            uint4 a2 = *(const uint4*)(&s_spk[2][4 * c]);
            uint4 a3 = *(const uint4*)(&s_spk[3][4 * c]);
            cI0 += __popc(m4.x & a0.x) + __popc(m4.y & a0.y)
                 + __popc(m4.z & a0.z) + __popc(m4.w & a0.w);
            cI1 += __popc(m4.x & a1.x) + __popc(m4.y & a1.y)
                 + __popc(m4.z & a1.z) + __popc(m4.w & a1.w);
            cI2 += __popc(m4.x & a2.x) + __popc(m4.y & a2.y)
                 + __popc(m4.z & a2.z) + __popc(m4.w & a2.w);
            cI3 += __popc(m4.x & a3.x) + __popc(m4.y & a3.y)
                 + __popc(m4.z & a3.z) + __popc(m4.w & a3.w);
        }
        {   // word 156 (inhibitory)
            uint32_t mL = s_mask156[tx];
            cI0 += __popc(mL & s_spk[0][156]);
            cI1 += __popc(mL & s_spk[1][156]);
            cI2 += __popc(mL & s_spk[2][156]);
            cI3 += __popc(mL & s_spk[3][156]);
        }

        // ---- 4 sequential neuron updates ----
#define BRUNEL_STEP(kk, xk)                                                   \
        {                                                                     \
            const int t = t0 + kk;                                            \
            float cur = 0.1f * (float)cE##kk - 0.5f * (float)cI##kk;          \
            v = v * 0.95f + (cur + xk);                                       \
            bool s = act && (v >= 1.0f);                                      \
            float sflag = s ? 1.0f : 0.0f;                                    \
            float vout  = s ? 0.0f : v;                                       \
            if (act) {                                                        \
                size_t o = ((size_t)t * NB + b) * NN + i;                     \
                out_spk[o] = sflag;                                           \
                out_vs[o]  = vout;                                            \
            }                                                                 \
            v = vout;                                                         \
            unsigned long long bm = __ballot(s);                              \
            if ((lane & 31) == 0 && act) {                                    \
                uint32_t wd = (lane == 0) ? (uint32_t)bm : (uint32_t)(bm >> 32); \
                ring[((size_t)(t & (RING_SLOTS - 1)) * NB + b) * RW + (i >> 5)] = wd; \
            }                                                                 \
        }
        BRUNEL_STEP(0, x0)
        BRUNEL_STEP(1, x1)
        BRUNEL_STEP(2, x2)
        BRUNEL_STEP(3, x3)
#undef BRUNEL_STEP

        // ---- arrive: release fence, one per-chunk atomic per block ----
        __threadfence();
        __syncthreads();
        if (tx == 0) atomicAdd(barc + (size_t)m * BARSTRIDE, 1);
    }
}

// ---------------------------------------------------------------------------
extern "C" void kernel_launch(void* const* d_in, const int* in_sizes, int n_in,
                              void* d_out, int out_size, void* d_ws, size_t ws_size,
                              hipStream_t stream)
{
    const float* ext = (const float*)d_in[0];   // [T,B,N] fp32
    const float* W   = (const float*)d_in[1];   // [N,N]   fp32

    float* out_spk = (float*)d_out;                          // [T,B,N]
    float* out_vs  = out_spk + (size_t)TSTEPS * NB * NN;     // [T,B,N]

    uint8_t*  ws   = (uint8_t*)d_ws;
    uint32_t* mask = (uint32_t*)(ws);
    int*      barc = (int*)(ws + BAR_OFF);
    uint32_t* ring = (uint32_t*)(ws + RING_OFF);

    // zero mask (pad columns must read 0) + per-chunk counters + ring
    hipMemsetAsync(ws, 0, ZERO_BYTES, stream);

    dim3 gmask(NIPAD / IPB, NN);   // (20, 5000)
    _Brunel_build_mask<<<gmask, IPB, 0, stream>>>(W, mask);

    _Brunel_persist<<<NBLK, IPB, 0, stream>>>(ext, mask, ring, barc,
                                              out_spk, out_vs);
}

// Round 8
// 475.935 us; speedup vs baseline: 7.2449x; 3.7555x over previous
//
#include <hip/hip_runtime.h>
#include <stdint.h>

// Problem constants (from reference)
#define NN      5000
#define NE      4000
#define NB      8
#define TSTEPS  256
#define NDELAY  15
#define NW      157          // uint32 words covering 5000 presyn bits
#define NIPAD   5120         // padded neuron dim (columns of maskT2)
#define RW      160          // ring/mask row stride in words
#define IPB     256          // threads per block
#define BPB     20           // blocks per batch
#define NBLK    (NB*BPB)     // 160 blocks -> 1 per CU, co-resident
#define RING_SLOTS 32
#define CH      4            // chunk length (64 chunks, no tail)
#define BARSTRIDE 16         // ints between chunk counters (64B apart)

// Workspace layout (bytes)
#define MASK_BYTES (RW*NIPAD*4)          // 3,276,800
#define BAR_OFF    MASK_BYTES
#define BAR_BYTES  (64*BARSTRIDE*4)      // 4,096 (64 chunk counters)
#define RING_OFF   (BAR_OFF + BAR_BYTES)
#define RING_BYTES (RING_SLOTS*NB*RW*4)  // 163,840
#define ZERO_BYTES (RING_OFF + RING_BYTES)

// ---------------------------------------------------------------------------
// Kernel 1: bit-pack connectivity, word-major-transposed:
//   maskT2[w*NIPAD + i] bit (j&31), w=j>>5, set iff W[i,j] != 0.
// ---------------------------------------------------------------------------
__global__ void _Brunel_build_mask(const float* __restrict__ W,
                                   uint32_t* __restrict__ maskT2)
{
    int j = blockIdx.x * blockDim.x + threadIdx.x;   // presyn 0..5119
    int i = blockIdx.y;                              // postsyn row 0..4999
    int lane = threadIdx.x & 63;
    bool nz = false;
    if (j < NN) nz = (W[(size_t)i * NN + j] != 0.0f);
    unsigned long long m = __ballot(nz);
    if ((lane & 31) == 0 && j < NN) {
        uint32_t wd = (lane == 0) ? (uint32_t)m : (uint32_t)(m >> 32);
        maskT2[(size_t)(j >> 5) * NIPAD + i] = wd;
    }
}

// ---------------------------------------------------------------------------
// Kernel 2: persistent SNN sim. Mask in LDS (thread-private rows), loaded
// once; inner loop identical to round 7 (bounded unroll, branch-free
// segments, scalar accumulators).
// Round-8 change: NO __threadfence() (agent fences = buffer_wbl2/buffer_inv,
// ~23us/chunk of L2 flush cost). Cross-block data (ring, barc) uses
// coherence-point accesses instead:
//   writes:  __hip_atomic_store RELAXED/AGENT  (sc0 sc1, bypasses L2)
//   reads:   __hip_atomic_load  RELAXED/AGENT  (sc0 sc1, bypasses L2)
//   arrive:  per-wave s_waitcnt vmcnt(0) -> __syncthreads -> relaxed add
// ---------------------------------------------------------------------------
__global__ void __launch_bounds__(IPB, 1) _Brunel_persist(
    const float* __restrict__ ext,
    const uint32_t* __restrict__ maskT2,
    uint32_t* __restrict__ ring,
    int* __restrict__ barc,
    float* __restrict__ out_spk,
    float* __restrict__ out_vs)
{
    const int tx   = threadIdx.x;
    const int bb   = blockIdx.x;
    const int b    = bb / BPB;
    const int i    = (bb % BPB) * IPB + tx;
    const bool act = (i < NN);
    const int lane = tx & 63;

    // LDS: mask rows (thread-private), stride 156 words = 624B (16B-aligned)
    __shared__ __align__(16) uint32_t s_mask[IPB][156];   // 159,744 B
    __shared__ uint32_t s_mask156[IPB];                   //   1,024 B
    __shared__ __align__(16) uint32_t s_spk[CH][RW];      //   2,560 B
                                                          // total 163,328 B

    // ---- one-time: mask row -> LDS (global reads coalesced over tx) ----
    for (int w = 0; w < NW; ++w) {
        uint32_t mv = maskT2[(size_t)w * NIPAD + i];      // pad cols are 0
        if (w < 156) s_mask[tx][w] = mv; else s_mask156[tx] = mv;
    }
    // zero spike staging (chunks 0..2 never stage; counts must be 0)
    for (int idx = tx; idx < CH * RW; idx += IPB)
        ((uint32_t*)s_spk)[idx] = 0u;
    __syncthreads();

    float v = 0.0f;

    for (int t0 = 0, m = 0; t0 < TSTEPS; t0 += CH, ++m) {
        // ---- prefetch external inputs ----
        float x0 = 0.f, x1 = 0.f, x2 = 0.f, x3 = 0.f;
        if (act) {
            const float* e0 = ext + ((size_t)t0 * NB + b) * NN + i;
            const size_t st = (size_t)NB * NN;
            x0 = e0[0]; x1 = e0[st]; x2 = e0[2 * st]; x3 = e0[3 * st];
        }

        // ---- wait for chunk m-3, then stage 4 delayed spike slots ----
        if (m >= 3) {
            if (tx == 0) {
                const int* c3 = barc + (size_t)(m - 3) * BARSTRIDE;
                while (__hip_atomic_load(c3, __ATOMIC_RELAXED,
                                         __HIP_MEMORY_SCOPE_AGENT) < NBLK)
                    __builtin_amdgcn_s_sleep(2);
            }
            __syncthreads();
            const int ts0 = t0 - NDELAY;     // may be -3 at m=3: slots hold 0
            for (int it = 0; it < (CH * RW + IPB - 1) / IPB; ++it) {
                int idx = tx + it * IPB;
                if (idx < CH * RW) {
                    int k = idx / RW, w = idx - k * RW;
                    int ts = ts0 + k;
                    ((uint32_t*)s_spk)[idx] = __hip_atomic_load(
                        &ring[((size_t)(ts & (RING_SLOTS - 1)) * NB + b) * RW + w],
                        __ATOMIC_RELAXED, __HIP_MEMORY_SCOPE_AGENT);
                }
            }
            __syncthreads();
        }

        // ---- synapse counts: mask uint4 read ONCE, used for all 4 steps ----
        int cE0 = 0, cE1 = 0, cE2 = 0, cE3 = 0;
        int cI0 = 0, cI1 = 0, cI2 = 0, cI3 = 0;
        const uint32_t* __restrict__ mrow = s_mask[tx];

#pragma unroll 4                       // bounded: no full-unroll spill
        for (int c = 0; c < 31; ++c) { // words 0..123: all excitatory
            uint4 m4 = *(const uint4*)(mrow + 4 * c);
            uint4 a0 = *(const uint4*)(&s_spk[0][4 * c]);
            uint4 a1 = *(const uint4*)(&s_spk[1][4 * c]);
            uint4 a2 = *(const uint4*)(&s_spk[2][4 * c]);
            uint4 a3 = *(const uint4*)(&s_spk[3][4 * c]);
            cE0 += __popc(m4.x & a0.x) + __popc(m4.y & a0.y)
                 + __popc(m4.z & a0.z) + __popc(m4.w & a0.w);
            cE1 += __popc(m4.x & a1.x) + __popc(m4.y & a1.y)
                 + __popc(m4.z & a1.z) + __popc(m4.w & a1.w);
            cE2 += __popc(m4.x & a2.x) + __popc(m4.y & a2.y)
                 + __popc(m4.z & a2.z) + __popc(m4.w & a2.w);
            cE3 += __popc(m4.x & a3.x) + __popc(m4.y & a3.y)
                 + __popc(m4.z & a3.z) + __popc(m4.w & a3.w);
        }
        {   // c = 31: word 124 excitatory, words 125..127 inhibitory
            uint4 m4 = *(const uint4*)(mrow + 124);
            uint4 a0 = *(const uint4*)(&s_spk[0][124]);
            uint4 a1 = *(const uint4*)(&s_spk[1][124]);
            uint4 a2 = *(const uint4*)(&s_spk[2][124]);
            uint4 a3 = *(const uint4*)(&s_spk[3][124]);
            cE0 += __popc(m4.x & a0.x);
            cI0 += __popc(m4.y & a0.y) + __popc(m4.z & a0.z) + __popc(m4.w & a0.w);
            cE1 += __popc(m4.x & a1.x);
            cI1 += __popc(m4.y & a1.y) + __popc(m4.z & a1.z) + __popc(m4.w & a1.w);
            cE2 += __popc(m4.x & a2.x);
            cI2 += __popc(m4.y & a2.y) + __popc(m4.z & a2.z) + __popc(m4.w & a2.w);
            cE3 += __popc(m4.x & a3.x);
            cI3 += __popc(m4.y & a3.y) + __popc(m4.z & a3.z) + __popc(m4.w & a3.w);
        }
#pragma unroll 4
        for (int c = 32; c < 39; ++c) { // words 128..155: all inhibitory
            uint4 m4 = *(const uint4*)(mrow + 4 * c);
            uint4 a0 = *(const uint4*)(&s_spk[0][4 * c]);
            uint4 a1 = *(const uint4*)(&s_spk[1][4 * c]);
            uint4 a2 = *(const uint4*)(&s_spk[2][4 * c]);
            uint4 a3 = *(const uint4*)(&s_spk[3][4 * c]);
            cI0 += __popc(m4.x & a0.x) + __popc(m4.y & a0.y)
                 + __popc(m4.z & a0.z) + __popc(m4.w & a0.w);
            cI1 += __popc(m4.x & a1.x) + __popc(m4.y & a1.y)
                 + __popc(m4.z & a1.z) + __popc(m4.w & a1.w);
            cI2 += __popc(m4.x & a2.x) + __popc(m4.y & a2.y)
                 + __popc(m4.z & a2.z) + __popc(m4.w & a2.w);
            cI3 += __popc(m4.x & a3.x) + __popc(m4.y & a3.y)
                 + __popc(m4.z & a3.z) + __popc(m4.w & a3.w);
        }
        {   // word 156 (inhibitory)
            uint32_t mL = s_mask156[tx];
            cI0 += __popc(mL & s_spk[0][156]);
            cI1 += __popc(mL & s_spk[1][156]);
            cI2 += __popc(mL & s_spk[2][156]);
            cI3 += __popc(mL & s_spk[3][156]);
        }

        // ---- 4 sequential neuron updates ----
#define BRUNEL_STEP(kk, xk)                                                   \
        {                                                                     \
            const int t = t0 + kk;                                            \
            float cur = 0.1f * (float)cE##kk - 0.5f * (float)cI##kk;          \
            v = v * 0.95f + (cur + xk);                                       \
            bool s = act && (v >= 1.0f);                                      \
            float sflag = s ? 1.0f : 0.0f;                                    \
            float vout  = s ? 0.0f : v;                                       \
            if (act) {                                                        \
                size_t o = ((size_t)t * NB + b) * NN + i;                     \
                out_spk[o] = sflag;                                           \
                out_vs[o]  = vout;                                            \
            }                                                                 \
            v = vout;                                                         \
            unsigned long long bm = __ballot(s);                              \
            if ((lane & 31) == 0 && act) {                                    \
                uint32_t wd = (lane == 0) ? (uint32_t)bm : (uint32_t)(bm >> 32); \
                __hip_atomic_store(                                           \
                    &ring[((size_t)(t & (RING_SLOTS - 1)) * NB + b) * RW + (i >> 5)], \
                    wd, __ATOMIC_RELAXED, __HIP_MEMORY_SCOPE_AGENT);          \
            }                                                                 \
        }
        BRUNEL_STEP(0, x0)
        BRUNEL_STEP(1, x1)
        BRUNEL_STEP(2, x2)
        BRUNEL_STEP(3, x3)
#undef BRUNEL_STEP

        // ---- arrive: per-wave store drain, block barrier, relaxed add ----
        asm volatile("s_waitcnt vmcnt(0)" ::: "memory");  // ring stores at LLC
        __syncthreads();                                  // all waves drained
        if (tx == 0)
            __hip_atomic_fetch_add(barc + (size_t)m * BARSTRIDE, 1,
                                   __ATOMIC_RELAXED, __HIP_MEMORY_SCOPE_AGENT);
    }
}

// ---------------------------------------------------------------------------
extern "C" void kernel_launch(void* const* d_in, const int* in_sizes, int n_in,
                              void* d_out, int out_size, void* d_ws, size_t ws_size,
                              hipStream_t stream)
{
    const float* ext = (const float*)d_in[0];   // [T,B,N] fp32
    const float* W   = (const float*)d_in[1];   // [N,N]   fp32

    float* out_spk = (float*)d_out;                          // [T,B,N]
    float* out_vs  = out_spk + (size_t)TSTEPS * NB * NN;     // [T,B,N]

    uint8_t*  ws   = (uint8_t*)d_ws;
    uint32_t* mask = (uint32_t*)(ws);
    int*      barc = (int*)(ws + BAR_OFF);
    uint32_t* ring = (uint32_t*)(ws + RING_OFF);

    // zero mask (pad columns must read 0) + per-chunk counters + ring
    hipMemsetAsync(ws, 0, ZERO_BYTES, stream);

    dim3 gmask(NIPAD / IPB, NN);   // (20, 5000)
    _Brunel_build_mask<<<gmask, IPB, 0, stream>>>(W, mask);

    _Brunel_persist<<<NBLK, IPB, 0, stream>>>(ext, mask, ring, barc,
                                              out_spk, out_vs);
}